// Round 16
// baseline (590.702 us; speedup 1.0000x reference)
//
#include <hip/hip_runtime.h>

#pragma clang fp contract(off)

#define BB 32
#define NN 8192
#define GG 256
#define KK 32

#define TB 1024   // 16 waves: waves 0-7 = batch half 0, waves 8-15 = half 1
#define TPB 512   // threads per batch
#define JPF 16    // points per thread

// f32 max DPP stage (row_ror / row_bcast). bound_ctrl=true -> masked lanes
// read 0.0f; fmax(self,0)==self for our non-negative values.
template <int CTRL>
__device__ __forceinline__ float dppmax_f(float v) {
  const int o =
      __builtin_amdgcn_update_dpp(0, __float_as_int(v), CTRL, 0xF, 0xF, true);
  return fmaxf(v, __int_as_float(o));
}

// one stage of a max-by-key float4 reduce over a period-8 lane pattern
template <int CTRL>
__device__ __forceinline__ float4 red_stage(float4 e) {
  float4 o;
  o.x = __int_as_float(
      __builtin_amdgcn_update_dpp(0, __float_as_int(e.x), CTRL, 0xF, 0xF, true));
  o.y = __int_as_float(
      __builtin_amdgcn_update_dpp(0, __float_as_int(e.y), CTRL, 0xF, 0xF, true));
  o.z = __int_as_float(
      __builtin_amdgcn_update_dpp(0, __float_as_int(e.z), CTRL, 0xF, 0xF, true));
  o.w = __int_as_float(
      __builtin_amdgcn_update_dpp(0, __float_as_int(e.w), CTRL, 0xF, 0xF, true));
  // keys are non-negative distance floats: uint compare == float compare
  const bool gt = __float_as_uint(o.w) > __float_as_uint(e.w);
  float4 r;
  r.x = gt ? o.x : e.x;
  r.y = gt ? o.y : e.y;
  r.z = gt ? o.z : e.z;
  r.w = gt ? o.w : e.w;
  return r;
}

// ---------- FPS: 2 batches per block (16 blocks x 1024 threads) ----------
__global__ __launch_bounds__(TB, 4) void fps_kernel(const float* __restrict__ xyz,
                                                    float* __restrict__ out) {
#pragma clang fp contract(off)
  const int t = threadIdx.x;
  const int lane = t & 63;
  const int wave = t >> 6;   // 0..15
  const int h = wave >> 3;   // batch half 0/1
  const int tb = t & (TPB - 1);
  const int batch = blockIdx.x * 2 + h;
  const float* __restrict__ P = xyz + (size_t)batch * NN * 3;

  __shared__ float4 wslot[2][16];  // per-wave winner {x,y,z,key}, dbuf

  float px[JPF], py[JPF], pz[JPF], md[JPF];
#pragma unroll
  for (int j = 0; j < JPF; ++j) {
    const int idx = tb + j * TPB;
    px[j] = P[idx * 3 + 0];
    py[j] = P[idx * 3 + 1];
    pz[j] = P[idx * 3 + 2];
    md[j] = __builtin_inff();
  }

  // center 0 = point 0 of this batch
  float cx = P[0], cy = P[1], cz = P[2];
  float sx = 0.f, sy = 0.f, sz = 0.f;  // thread tb records center tb
  if (tb == 0) { sx = cx; sy = cy; sz = cz; }

  for (int i = 0; i < GG - 1; ++i) {
    // distance update; VALUE-only max tracking
    float bv = -1.0f;
#pragma unroll
    for (int j = 0; j < JPF; ++j) {
      const float dx = px[j] - cx;
      const float dy = py[j] - cy;
      const float dz = pz[j] - cz;
      const float d = dx * dx + dy * dy + dz * dz;  // ((x2+y2)+z2), no FMA
      const float m = md[j] < d ? md[j] : d;
      md[j] = m;
      bv = fmaxf(bv, m);
    }

    // wave max via 6 DPP stages -> lane 63 -> SGPR broadcast
    float v = bv;
    v = dppmax_f<0x121>(v);  // row_ror:1
    v = dppmax_f<0x122>(v);  // row_ror:2
    v = dppmax_f<0x124>(v);  // row_ror:4
    v = dppmax_f<0x128>(v);  // row_ror:8
    v = dppmax_f<0x142>(v);  // row_bcast15
    v = dppmax_f<0x143>(v);  // row_bcast31 -> lane 63 = wave max
    const unsigned Mw =
        (unsigned)__builtin_amdgcn_readlane(__float_as_int(v), 63);

    // winner lane = first candidate lane; it selects its winning point's
    // coords with COMPILE-TIME indices and writes one b128 slot
    const bool cand = (__float_as_uint(bv) == Mw);
    const unsigned long long bal = __ballot(cand);
    const int wl = __ffsll((long long)bal) - 1;
    if (lane == wl) {
      float wx = px[0], wy = py[0], wz = pz[0];
#pragma unroll
      for (int j = JPF - 1; j >= 0; --j) {
        if (__float_as_uint(md[j]) == Mw) { wx = px[j]; wy = py[j]; wz = pz[j]; }
      }
      wslot[i & 1][wave] = make_float4(wx, wy, wz, __uint_as_float(Mw));
    }
    __syncthreads();

    // each lane reads one of its batch's 8 slots; 3-stage DPP max-by-key
    float4 e = wslot[i & 1][h * 8 + (lane & 7)];
    e = red_stage<0x121>(e);  // ror 1
    e = red_stage<0x122>(e);  // ror 2
    e = red_stage<0x124>(e);  // ror 4  -> batch winner in every lane
    cx = e.x; cy = e.y; cz = e.z;
    if (tb == i + 1) { sx = cx; sy = cy; sz = cz; }
  }

  // write all centers once (off the critical loop)
  if (tb < GG) {
    float* __restrict__ co =
        out + (size_t)BB * GG * KK * 3 + ((size_t)batch * GG + tb) * 3;
    co[0] = sx; co[1] = sy; co[2] = sz;
  }
}

// ---------------- KNN + gather: 8 blocks per batch (R14 verbatim) --------
__global__ __launch_bounds__(512, 1) void knn_kernel(const float* __restrict__ xyz,
                                                     float* __restrict__ out) {
#pragma clang fp contract(off)
  const int b = blockIdx.x >> 3;
  const int chunk = blockIdx.x & 7;
  const int t = threadIdx.x;
  const int lane = t & 63;
  const int wave = t >> 6;
  const float* __restrict__ P = xyz + (size_t)b * NN * 3;

  __shared__ float4 pts4[NN];                       // 128 KB
  __shared__ unsigned long long cand[8][256];       // 16 KB per-wave buffer

  for (int pt = t; pt < NN; pt += 512)
    pts4[pt] = make_float4(P[pt * 3 + 0], P[pt * 3 + 1], P[pt * 3 + 2], 0.0f);
  __syncthreads();

  const float* __restrict__ cent = out + (size_t)BB * GG * KK * 3;
  const int gbase = chunk * 32 + wave * 4;

  const float c0x = cent[((size_t)b * GG + gbase + 0) * 3 + 0];
  const float c0y = cent[((size_t)b * GG + gbase + 0) * 3 + 1];
  const float c0z = cent[((size_t)b * GG + gbase + 0) * 3 + 2];
  const float c1x = cent[((size_t)b * GG + gbase + 1) * 3 + 0];
  const float c1y = cent[((size_t)b * GG + gbase + 1) * 3 + 1];
  const float c1z = cent[((size_t)b * GG + gbase + 1) * 3 + 2];
  const float c2x = cent[((size_t)b * GG + gbase + 2) * 3 + 0];
  const float c2y = cent[((size_t)b * GG + gbase + 2) * 3 + 1];
  const float c2z = cent[((size_t)b * GG + gbase + 2) * 3 + 2];
  const float c3x = cent[((size_t)b * GG + gbase + 3) * 3 + 0];
  const float c3y = cent[((size_t)b * GG + gbase + 3) * 3 + 1];
  const float c3z = cent[((size_t)b * GG + gbase + 3) * 3 + 2];

  // Pass 1 (fused): one sweep, 4 running minima
  float mn0 = __builtin_inff(), mn1 = __builtin_inff();
  float mn2 = __builtin_inff(), mn3 = __builtin_inff();
#pragma unroll 4
  for (int j = 0; j < 128; ++j) {
    const float4 p = pts4[lane + j * 64];
    {
      const float dx = p.x - c0x, dy = p.y - c0y, dz = p.z - c0z;
      mn0 = fminf(mn0, dx * dx + dy * dy + dz * dz);
    }
    {
      const float dx = p.x - c1x, dy = p.y - c1y, dz = p.z - c1z;
      mn1 = fminf(mn1, dx * dx + dy * dy + dz * dz);
    }
    {
      const float dx = p.x - c2x, dy = p.y - c2y, dz = p.z - c2z;
      mn2 = fminf(mn2, dx * dx + dy * dy + dz * dz);
    }
    {
      const float dx = p.x - c3x, dy = p.y - c3y, dz = p.z - c3z;
      mn3 = fminf(mn3, dx * dx + dy * dy + dz * dz);
    }
  }

  auto thresh = [&](float mn) -> float {
    float sm = mn;
#pragma unroll
    for (int k = 2; k <= 64; k <<= 1) {
#pragma unroll
      for (int j2 = k >> 1; j2 > 0; j2 >>= 1) {
        const float o = __shfl_xor(sm, j2, 64);
        const bool keepMin = (((lane & k) == 0) == ((lane & j2) == 0));
        sm = keepMin ? fminf(sm, o) : fmaxf(sm, o);
      }
    }
    const float v = __shfl(sm, 31, 64);
    return __uint_as_float(__float_as_uint(v) + 8);
  };
  const float vi0 = thresh(mn0);
  const float vi1 = thresh(mn1);
  const float vi2 = thresh(mn2);
  const float vi3 = thresh(mn3);

  auto dogroup = [&](int g, float cx, float cy, float cz, float vi) {
    unsigned cnt = 0;
    unsigned long long* __restrict__ cb = cand[wave];
#pragma unroll 4
    for (int j = 0; j < 128; ++j) {
      const int idx = lane + j * 64;
      const float4 p = pts4[idx];
      const float dx = p.x - cx, dy = p.y - cy, dz = p.z - cz;
      const float d2 = dx * dx + dy * dy + dz * dz;  // no FMA
      const bool pr = d2 <= vi;
      const unsigned long long mk = __ballot(pr);
      if (pr) {
        const unsigned off = cnt + (unsigned)__popcll(mk & ((1ull << lane) - 1));
        if (off < 256)
          cb[off] = ((unsigned long long)__float_as_uint(d2) << 32) |
                    (unsigned)idx;
      }
      cnt += (unsigned)__popcll(mk);
    }
    if (cnt > 256) cnt = 256;

    auto conv = [](unsigned long long e) -> unsigned long long {
      const float d = sqrtf(__uint_as_float((unsigned)(e >> 32)));
      return ((unsigned long long)__float_as_uint(d) << 32) | (e & 0xFFFFFFFFull);
    };

    unsigned long long myk;
    if (cnt <= 64) {
      unsigned long long key = ~0ull;
      if ((unsigned)lane < cnt) key = conv(cb[lane]);
#pragma unroll
      for (int k = 2; k <= 64; k <<= 1) {
#pragma unroll
        for (int j2 = k >> 1; j2 > 0; j2 >>= 1) {
          const unsigned long long o = __shfl_xor(key, j2, 64);
          const bool keepMin = (((lane & k) == 0) == ((lane & j2) == 0));
          const unsigned long long lo = o < key ? o : key;
          const unsigned long long hi = o < key ? key : o;
          key = keepMin ? lo : hi;
        }
      }
      myk = key;
    } else {
      unsigned long long k0 = ~0ull, k1 = ~0ull, k2 = ~0ull, k3 = ~0ull;
      if ((unsigned)lane < cnt)         k0 = conv(cb[lane]);
      if ((unsigned)(lane + 64) < cnt)  k1 = conv(cb[lane + 64]);
      if ((unsigned)(lane + 128) < cnt) k2 = conv(cb[lane + 128]);
      if ((unsigned)(lane + 192) < cnt) k3 = conv(cb[lane + 192]);
      unsigned long long got = ~0ull;
      for (int r = 0; r < 32; ++r) {
        unsigned long long m01 = k0 < k1 ? k0 : k1;
        unsigned long long m23 = k2 < k3 ? k2 : k3;
        unsigned long long m = m01 < m23 ? m01 : m23;
#pragma unroll
        for (int s = 32; s > 0; s >>= 1) {
          const unsigned long long o = __shfl_xor(m, s, 64);
          m = o < m ? o : m;
        }
        if (lane == r) got = m;
        if (k0 == m) k0 = ~0ull;
        else if (k1 == m) k1 = ~0ull;
        else if (k2 == m) k2 = ~0ull;
        else if (k3 == m) k3 = ~0ull;
      }
      myk = got;
    }

    if (lane < KK) {
      const unsigned idx = (unsigned)(myk & 0xFFFFFFFFull);
      const float4 p = pts4[idx];
      float* __restrict__ po =
          out + ((size_t)(((size_t)b * GG + g) * KK + lane)) * 3;
      po[0] = p.x - cx; po[1] = p.y - cy; po[2] = p.z - cz;
    }
  };

  dogroup(gbase + 0, c0x, c0y, c0z, vi0);
  dogroup(gbase + 1, c1x, c1y, c1z, vi1);
  dogroup(gbase + 2, c2x, c2y, c2z, vi2);
  dogroup(gbase + 3, c3x, c3y, c3z, vi3);
}

extern "C" void kernel_launch(void* const* d_in, const int* in_sizes, int n_in,
                              void* d_out, int out_size, void* d_ws, size_t ws_size,
                              hipStream_t stream) {
  const float* xyz = (const float*)d_in[0];
  float* out = (float*)d_out;
  fps_kernel<<<dim3(BB / 2), dim3(TB), 0, stream>>>(xyz, out);
  knn_kernel<<<dim3(BB * 8), dim3(512), 0, stream>>>(xyz, out);
}

// Round 17
// 424.806 us; speedup vs baseline: 1.3905x; 1.3905x over previous
//
#include <hip/hip_runtime.h>

#pragma clang fp contract(off)

#define BB 32
#define NN 8192
#define GG 256
#define KK 32

#define TFPS 512
#define JPF (NN / TFPS)  // 16 points per thread

// f32 max DPP stage (row_ror / row_bcast). bound_ctrl=true -> masked lanes
// read 0.0f; fmax(self,0)==self for our non-negative values.
template <int CTRL>
__device__ __forceinline__ float dppmax_f(float v) {
  const int o =
      __builtin_amdgcn_update_dpp(0, __float_as_int(v), CTRL, 0xF, 0xF, true);
  return fmaxf(v, __int_as_float(o));
}

// one stage of a max-by-key float4 reduce over a period-8 lane pattern
template <int CTRL>
__device__ __forceinline__ float4 red_stage(float4 e) {
  float4 o;
  o.x = __int_as_float(
      __builtin_amdgcn_update_dpp(0, __float_as_int(e.x), CTRL, 0xF, 0xF, true));
  o.y = __int_as_float(
      __builtin_amdgcn_update_dpp(0, __float_as_int(e.y), CTRL, 0xF, 0xF, true));
  o.z = __int_as_float(
      __builtin_amdgcn_update_dpp(0, __float_as_int(e.z), CTRL, 0xF, 0xF, true));
  o.w = __int_as_float(
      __builtin_amdgcn_update_dpp(0, __float_as_int(e.w), CTRL, 0xF, 0xF, true));
  // keys are non-negative distance floats: uint compare == float compare
  const bool gt = __float_as_uint(o.w) > __float_as_uint(e.w);
  float4 r;
  r.x = gt ? o.x : e.x;
  r.y = gt ? o.y : e.y;
  r.z = gt ? o.z : e.z;
  r.w = gt ? o.w : e.w;
  return r;
}

// ---------- FPS: one block per batch, 512 threads, 1 barrier/step ----------
__global__ __launch_bounds__(TFPS, 1) void fps_kernel(const float* __restrict__ xyz,
                                                      float* __restrict__ out) {
#pragma clang fp contract(off)
  const int t = threadIdx.x;
  const int lane = t & 63;
  const int wave = t >> 6;  // 0..7
  const int batch = blockIdx.x;
  const float* __restrict__ P = xyz + (size_t)batch * NN * 3;

  __shared__ float4 wslot[2][8];  // per-wave winner {x,y,z,key}, dbuf

  float px[JPF], py[JPF], pz[JPF], md[JPF];
#pragma unroll
  for (int j = 0; j < JPF; ++j) {
    const int idx = t + j * TFPS;
    px[j] = P[idx * 3 + 0];
    py[j] = P[idx * 3 + 1];
    pz[j] = P[idx * 3 + 2];
    md[j] = __builtin_inff();
  }

  // center 0 = point 0 of this batch (uniform scalar loads, once)
  float cx = P[0], cy = P[1], cz = P[2];
  float sx = 0.f, sy = 0.f, sz = 0.f;  // thread t records center t
  if (t == 0) { sx = cx; sy = cy; sz = cz; }

  for (int i = 0; i < GG - 1; ++i) {
    // distance update; VALUE-only max tracking
    float bv = -1.0f;
#pragma unroll
    for (int j = 0; j < JPF; ++j) {
      const float dx = px[j] - cx;
      const float dy = py[j] - cy;
      const float dz = pz[j] - cz;
      const float d = dx * dx + dy * dy + dz * dz;  // ((x2+y2)+z2), no FMA
      const float m = md[j] < d ? md[j] : d;
      md[j] = m;
      bv = fmaxf(bv, m);
    }

    // wave max via 6 DPP stages -> lane 63 -> SGPR broadcast
    float v = bv;
    v = dppmax_f<0x121>(v);  // row_ror:1
    v = dppmax_f<0x122>(v);  // row_ror:2
    v = dppmax_f<0x124>(v);  // row_ror:4
    v = dppmax_f<0x128>(v);  // row_ror:8
    v = dppmax_f<0x142>(v);  // row_bcast15
    v = dppmax_f<0x143>(v);  // row_bcast31 -> lane 63 = wave max
    const unsigned Mw =
        (unsigned)__builtin_amdgcn_readlane(__float_as_int(v), 63);

    // winner lane = first candidate lane; it selects its winning point's
    // coords with COMPILE-TIME indices and writes one b128 slot
    const bool cand = (__float_as_uint(bv) == Mw);
    const unsigned long long bal = __ballot(cand);
    const int wl = __ffsll((long long)bal) - 1;
    if (lane == wl) {
      float wx = px[0], wy = py[0], wz = pz[0];
#pragma unroll
      for (int j = JPF - 1; j >= 0; --j) {
        if (__float_as_uint(md[j]) == Mw) { wx = px[j]; wy = py[j]; wz = pz[j]; }
      }
      wslot[i & 1][wave] = make_float4(wx, wy, wz, __uint_as_float(Mw));
    }
    __syncthreads();  // the ONLY barrier per step

    // each lane reads one of the 8 slots (8-lane broadcast groups, conflict-
    // free); 3-stage DPP max-by-key -> block winner coords in every lane
    float4 e = wslot[i & 1][lane & 7];
    e = red_stage<0x121>(e);  // ror 1
    e = red_stage<0x122>(e);  // ror 2
    e = red_stage<0x124>(e);  // ror 4
    cx = e.x; cy = e.y; cz = e.z;
    if (t == i + 1) { sx = cx; sy = cy; sz = cz; }
  }

  // write all centers once (off the critical loop)
  if (t < GG) {
    float* __restrict__ co =
        out + (size_t)BB * GG * KK * 3 + ((size_t)batch * GG + t) * 3;
    co[0] = sx; co[1] = sy; co[2] = sz;
  }
}

// ---------------- KNN + gather: 8 blocks per batch (R14 verbatim) --------
__global__ __launch_bounds__(512, 1) void knn_kernel(const float* __restrict__ xyz,
                                                     float* __restrict__ out) {
#pragma clang fp contract(off)
  const int b = blockIdx.x >> 3;
  const int chunk = blockIdx.x & 7;
  const int t = threadIdx.x;
  const int lane = t & 63;
  const int wave = t >> 6;
  const float* __restrict__ P = xyz + (size_t)b * NN * 3;

  __shared__ float4 pts4[NN];                       // 128 KB
  __shared__ unsigned long long cand[8][256];       // 16 KB per-wave buffer

  for (int pt = t; pt < NN; pt += 512)
    pts4[pt] = make_float4(P[pt * 3 + 0], P[pt * 3 + 1], P[pt * 3 + 2], 0.0f);
  __syncthreads();

  const float* __restrict__ cent = out + (size_t)BB * GG * KK * 3;
  const int gbase = chunk * 32 + wave * 4;

  const float c0x = cent[((size_t)b * GG + gbase + 0) * 3 + 0];
  const float c0y = cent[((size_t)b * GG + gbase + 0) * 3 + 1];
  const float c0z = cent[((size_t)b * GG + gbase + 0) * 3 + 2];
  const float c1x = cent[((size_t)b * GG + gbase + 1) * 3 + 0];
  const float c1y = cent[((size_t)b * GG + gbase + 1) * 3 + 1];
  const float c1z = cent[((size_t)b * GG + gbase + 1) * 3 + 2];
  const float c2x = cent[((size_t)b * GG + gbase + 2) * 3 + 0];
  const float c2y = cent[((size_t)b * GG + gbase + 2) * 3 + 1];
  const float c2z = cent[((size_t)b * GG + gbase + 2) * 3 + 2];
  const float c3x = cent[((size_t)b * GG + gbase + 3) * 3 + 0];
  const float c3y = cent[((size_t)b * GG + gbase + 3) * 3 + 1];
  const float c3z = cent[((size_t)b * GG + gbase + 3) * 3 + 2];

  // Pass 1 (fused): one sweep, 4 running minima
  float mn0 = __builtin_inff(), mn1 = __builtin_inff();
  float mn2 = __builtin_inff(), mn3 = __builtin_inff();
#pragma unroll 4
  for (int j = 0; j < 128; ++j) {
    const float4 p = pts4[lane + j * 64];
    {
      const float dx = p.x - c0x, dy = p.y - c0y, dz = p.z - c0z;
      mn0 = fminf(mn0, dx * dx + dy * dy + dz * dz);
    }
    {
      const float dx = p.x - c1x, dy = p.y - c1y, dz = p.z - c1z;
      mn1 = fminf(mn1, dx * dx + dy * dy + dz * dz);
    }
    {
      const float dx = p.x - c2x, dy = p.y - c2y, dz = p.z - c2z;
      mn2 = fminf(mn2, dx * dx + dy * dy + dz * dz);
    }
    {
      const float dx = p.x - c3x, dy = p.y - c3y, dz = p.z - c3z;
      mn3 = fminf(mn3, dx * dx + dy * dy + dz * dz);
    }
  }

  auto thresh = [&](float mn) -> float {
    float sm = mn;
#pragma unroll
    for (int k = 2; k <= 64; k <<= 1) {
#pragma unroll
      for (int j2 = k >> 1; j2 > 0; j2 >>= 1) {
        const float o = __shfl_xor(sm, j2, 64);
        const bool keepMin = (((lane & k) == 0) == ((lane & j2) == 0));
        sm = keepMin ? fminf(sm, o) : fmaxf(sm, o);
      }
    }
    const float v = __shfl(sm, 31, 64);
    return __uint_as_float(__float_as_uint(v) + 8);
  };
  const float vi0 = thresh(mn0);
  const float vi1 = thresh(mn1);
  const float vi2 = thresh(mn2);
  const float vi3 = thresh(mn3);

  auto dogroup = [&](int g, float cx, float cy, float cz, float vi) {
    unsigned cnt = 0;
    unsigned long long* __restrict__ cb = cand[wave];
#pragma unroll 4
    for (int j = 0; j < 128; ++j) {
      const int idx = lane + j * 64;
      const float4 p = pts4[idx];
      const float dx = p.x - cx, dy = p.y - cy, dz = p.z - cz;
      const float d2 = dx * dx + dy * dy + dz * dz;  // no FMA
      const bool pr = d2 <= vi;
      const unsigned long long mk = __ballot(pr);
      if (pr) {
        const unsigned off = cnt + (unsigned)__popcll(mk & ((1ull << lane) - 1));
        if (off < 256)
          cb[off] = ((unsigned long long)__float_as_uint(d2) << 32) |
                    (unsigned)idx;
      }
      cnt += (unsigned)__popcll(mk);
    }
    if (cnt > 256) cnt = 256;

    auto conv = [](unsigned long long e) -> unsigned long long {
      const float d = sqrtf(__uint_as_float((unsigned)(e >> 32)));
      return ((unsigned long long)__float_as_uint(d) << 32) | (e & 0xFFFFFFFFull);
    };

    unsigned long long myk;
    if (cnt <= 64) {
      unsigned long long key = ~0ull;
      if ((unsigned)lane < cnt) key = conv(cb[lane]);
#pragma unroll
      for (int k = 2; k <= 64; k <<= 1) {
#pragma unroll
        for (int j2 = k >> 1; j2 > 0; j2 >>= 1) {
          const unsigned long long o = __shfl_xor(key, j2, 64);
          const bool keepMin = (((lane & k) == 0) == ((lane & j2) == 0));
          const unsigned long long lo = o < key ? o : key;
          const unsigned long long hi = o < key ? key : o;
          key = keepMin ? lo : hi;
        }
      }
      myk = key;
    } else {
      unsigned long long k0 = ~0ull, k1 = ~0ull, k2 = ~0ull, k3 = ~0ull;
      if ((unsigned)lane < cnt)         k0 = conv(cb[lane]);
      if ((unsigned)(lane + 64) < cnt)  k1 = conv(cb[lane + 64]);
      if ((unsigned)(lane + 128) < cnt) k2 = conv(cb[lane + 128]);
      if ((unsigned)(lane + 192) < cnt) k3 = conv(cb[lane + 192]);
      unsigned long long got = ~0ull;
      for (int r = 0; r < 32; ++r) {
        unsigned long long m01 = k0 < k1 ? k0 : k1;
        unsigned long long m23 = k2 < k3 ? k2 : k3;
        unsigned long long m = m01 < m23 ? m01 : m23;
#pragma unroll
        for (int s = 32; s > 0; s >>= 1) {
          const unsigned long long o = __shfl_xor(m, s, 64);
          m = o < m ? o : m;
        }
        if (lane == r) got = m;
        if (k0 == m) k0 = ~0ull;
        else if (k1 == m) k1 = ~0ull;
        else if (k2 == m) k2 = ~0ull;
        else if (k3 == m) k3 = ~0ull;
      }
      myk = got;
    }

    if (lane < KK) {
      const unsigned idx = (unsigned)(myk & 0xFFFFFFFFull);
      const float4 p = pts4[idx];
      float* __restrict__ po =
          out + ((size_t)(((size_t)b * GG + g) * KK + lane)) * 3;
      po[0] = p.x - cx; po[1] = p.y - cy; po[2] = p.z - cz;
    }
  };

  dogroup(gbase + 0, c0x, c0y, c0z, vi0);
  dogroup(gbase + 1, c1x, c1y, c1z, vi1);
  dogroup(gbase + 2, c2x, c2y, c2z, vi2);
  dogroup(gbase + 3, c3x, c3y, c3z, vi3);
}

extern "C" void kernel_launch(void* const* d_in, const int* in_sizes, int n_in,
                              void* d_out, int out_size, void* d_ws, size_t ws_size,
                              hipStream_t stream) {
  const float* xyz = (const float*)d_in[0];
  float* out = (float*)d_out;
  fps_kernel<<<dim3(BB), dim3(TFPS), 0, stream>>>(xyz, out);
  knn_kernel<<<dim3(BB * 8), dim3(512), 0, stream>>>(xyz, out);
}

// Round 18
// 319.221 us; speedup vs baseline: 1.8505x; 1.3308x over previous
//
#include <hip/hip_runtime.h>

#pragma clang fp contract(off)

#define BB 32
#define NN 8192
#define GG 256
#define KK 32

#define TFPS 512
#define JPF (NN / TFPS)  // 16 points per thread

// f32 max over a 16-lane row via DPP row_ror (pure VALU).
template <int CTRL>
__device__ __forceinline__ float rot_maxf(float v) {
  const int o =
      __builtin_amdgcn_update_dpp(0, __float_as_int(v), CTRL, 0xF, 0xF, true);
  return fmaxf(v, __int_as_float(o));
}

// ---------------- FPS: one block per batch, 512 threads (R7 verbatim) -----
__global__ __launch_bounds__(TFPS, 1) void fps_kernel(const float* __restrict__ xyz,
                                                      float* __restrict__ out) {
#pragma clang fp contract(off)
  const int b = blockIdx.x;
  const int t = threadIdx.x;
  const int lane = t & 63;
  const int wave = t >> 6;  // 0..7
  const float* __restrict__ P = xyz + (size_t)b * NN * 3;

  __shared__ float4 pts[NN];          // 128 KB: 1 ds_read_b128 per broadcast
  __shared__ float rowmax[2][32];     // 8 waves x 4 rows, double-buffered
  __shared__ unsigned winIdx[2];      // argmin-index slots, double-buffered

  float px[JPF], py[JPF], pz[JPF], md[JPF];
#pragma unroll
  for (int j = 0; j < JPF; ++j) {
    const int idx = t + j * TFPS;
    const float x = P[idx * 3 + 0];
    const float y = P[idx * 3 + 1];
    const float z = P[idx * 3 + 2];
    px[j] = x; py[j] = y; pz[j] = z;
    md[j] = __builtin_inff();
    pts[idx] = make_float4(x, y, z, 0.0f);
  }
  if (t == 0) { winIdx[0] = 0xFFFFFFFFu; winIdx[1] = 0xFFFFFFFFu; }
  __syncthreads();

  unsigned win = 0;      // first center = index 0
  unsigned mywin = 0;    // thread t<GG records the step-t winner

  for (int i = 0; i < GG; ++i) {
    if (t == i) mywin = win;
    if (i == GG - 1) break;

    // broadcast winner coords from LDS (single b128, uniform address)
    const float4 c = pts[win];
    const float cx = c.x, cy = c.y, cz = c.z;

    // distance update; track only the VALUE of the local max (no index ops)
    float bv = -1.0f;
#pragma unroll
    for (int j = 0; j < JPF; ++j) {
      const float dx = px[j] - cx;
      const float dy = py[j] - cy;
      const float dz = pz[j] - cz;
      const float d = dx * dx + dy * dy + dz * dz;  // ((x2+y2)+z2), no FMA
      const float m = md[j] < d ? md[j] : d;
      md[j] = m;
      bv = fmaxf(bv, m);
    }

    // level 1: 16-lane row max via DPP rotations (f32 only)
    float r = bv;
    r = rot_maxf<0x121>(r);  // ror 1
    r = rot_maxf<0x122>(r);  // ror 2
    r = rot_maxf<0x124>(r);  // ror 4
    r = rot_maxf<0x128>(r);  // ror 8
    if ((lane & 15) == 0)
      rowmax[i & 1][wave * 4 + (lane >> 4)] = r;
    __syncthreads();  // barrier 1

    // reset the OTHER buffer's index slot for step i+1
    if (t == 0) winIdx[(i + 1) & 1] = 0xFFFFFFFFu;

    // level 2: 32 row-maxes -> global max M in every lane (f32 only)
    const float* __restrict__ rm = rowmax[i & 1];
    const int g = lane & 15;
    float m2 = fmaxf(rm[g], rm[g + 16]);
    m2 = rot_maxf<0x121>(m2);
    m2 = rot_maxf<0x122>(m2);
    m2 = rot_maxf<0x124>(m2);
    m2 = rot_maxf<0x128>(m2);
    const float M = m2;

    // index recovery: only threads holding the max rescan (execz-skipped in
    // waves with no candidate); smallest global index wins (== first argmax)
    if (bv == M) {
      int fj = 0;
#pragma unroll
      for (int j = JPF - 1; j >= 0; --j)
        if (md[j] == M) fj = j;
      atomicMin(&winIdx[i & 1], (unsigned)t + ((unsigned)fj << 9));  // fj*512
    }
    __syncthreads();  // barrier 2

    win = winIdx[i & 1];
  }

  // write all centers once (off the critical loop)
  if (t < GG) {
    const float4 c = pts[mywin];
    float* __restrict__ co =
        out + (size_t)BB * GG * KK * 3 + ((size_t)b * GG + t) * 3;
    co[0] = c.x; co[1] = c.y; co[2] = c.z;
  }
}

// ---------------- KNN + gather: 8 blocks per batch ----------------
// float4 LDS staging (1 b128/point) + pass-1 fused across the wave's 4 groups.
__global__ __launch_bounds__(512, 1) void knn_kernel(const float* __restrict__ xyz,
                                                     float* __restrict__ out) {
#pragma clang fp contract(off)
  const int b = blockIdx.x >> 3;
  const int chunk = blockIdx.x & 7;
  const int t = threadIdx.x;
  const int lane = t & 63;
  const int wave = t >> 6;
  const float* __restrict__ P = xyz + (size_t)b * NN * 3;

  __shared__ float4 pts4[NN];                       // 128 KB
  __shared__ unsigned long long cand[8][256];       // 16 KB per-wave buffer

  for (int pt = t; pt < NN; pt += 512)
    pts4[pt] = make_float4(P[pt * 3 + 0], P[pt * 3 + 1], P[pt * 3 + 2], 0.0f);
  __syncthreads();

  const float* __restrict__ cent = out + (size_t)BB * GG * KK * 3;
  const int gbase = chunk * 32 + wave * 4;

  // load the wave's 4 centers into named scalars (compile-time indices only)
  const float c0x = cent[((size_t)b * GG + gbase + 0) * 3 + 0];
  const float c0y = cent[((size_t)b * GG + gbase + 0) * 3 + 1];
  const float c0z = cent[((size_t)b * GG + gbase + 0) * 3 + 2];
  const float c1x = cent[((size_t)b * GG + gbase + 1) * 3 + 0];
  const float c1y = cent[((size_t)b * GG + gbase + 1) * 3 + 1];
  const float c1z = cent[((size_t)b * GG + gbase + 1) * 3 + 2];
  const float c2x = cent[((size_t)b * GG + gbase + 2) * 3 + 0];
  const float c2y = cent[((size_t)b * GG + gbase + 2) * 3 + 1];
  const float c2z = cent[((size_t)b * GG + gbase + 2) * 3 + 2];
  const float c3x = cent[((size_t)b * GG + gbase + 3) * 3 + 0];
  const float c3y = cent[((size_t)b * GG + gbase + 3) * 3 + 1];
  const float c3z = cent[((size_t)b * GG + gbase + 3) * 3 + 2];

  // Pass 1 (fused): one sweep, 4 running minima
  float mn0 = __builtin_inff(), mn1 = __builtin_inff();
  float mn2 = __builtin_inff(), mn3 = __builtin_inff();
#pragma unroll 4
  for (int j = 0; j < 128; ++j) {
    const float4 p = pts4[lane + j * 64];
    {
      const float dx = p.x - c0x, dy = p.y - c0y, dz = p.z - c0z;
      mn0 = fminf(mn0, dx * dx + dy * dy + dz * dz);
    }
    {
      const float dx = p.x - c1x, dy = p.y - c1y, dz = p.z - c1z;
      mn1 = fminf(mn1, dx * dx + dy * dy + dz * dz);
    }
    {
      const float dx = p.x - c2x, dy = p.y - c2y, dz = p.z - c2z;
      mn2 = fminf(mn2, dx * dx + dy * dy + dz * dz);
    }
    {
      const float dx = p.x - c3x, dy = p.y - c3y, dz = p.z - c3z;
      mn3 = fminf(mn3, dx * dx + dy * dy + dz * dz);
    }
  }

  // threshold = 32nd-smallest of the 64 per-lane minima (+8 ulp guard)
  auto thresh = [&](float mn) -> float {
    float sm = mn;
#pragma unroll
    for (int k = 2; k <= 64; k <<= 1) {
#pragma unroll
      for (int j2 = k >> 1; j2 > 0; j2 >>= 1) {
        const float o = __shfl_xor(sm, j2, 64);
        const bool keepMin = (((lane & k) == 0) == ((lane & j2) == 0));
        sm = keepMin ? fminf(sm, o) : fmaxf(sm, o);
      }
    }
    const float v = __shfl(sm, 31, 64);
    return __uint_as_float(__float_as_uint(v) + 8);
  };
  const float vi0 = thresh(mn0);
  const float vi1 = thresh(mn1);
  const float vi2 = thresh(mn2);
  const float vi3 = thresh(mn3);

  // Pass 2 per group: recompute d2 (bit-identical), compact, sort, store
  auto dogroup = [&](int g, float cx, float cy, float cz, float vi) {
    unsigned cnt = 0;
    unsigned long long* __restrict__ cb = cand[wave];
#pragma unroll 4
    for (int j = 0; j < 128; ++j) {
      const int idx = lane + j * 64;
      const float4 p = pts4[idx];
      const float dx = p.x - cx, dy = p.y - cy, dz = p.z - cz;
      const float d2 = dx * dx + dy * dy + dz * dz;  // no FMA
      const bool pr = d2 <= vi;
      const unsigned long long mk = __ballot(pr);
      if (pr) {
        const unsigned off = cnt + (unsigned)__popcll(mk & ((1ull << lane) - 1));
        if (off < 256)
          cb[off] = ((unsigned long long)__float_as_uint(d2) << 32) |
                    (unsigned)idx;
      }
      cnt += (unsigned)__popcll(mk);
    }
    if (cnt > 256) cnt = 256;

    auto conv = [](unsigned long long e) -> unsigned long long {
      const float d = sqrtf(__uint_as_float((unsigned)(e >> 32)));
      return ((unsigned long long)__float_as_uint(d) << 32) | (e & 0xFFFFFFFFull);
    };

    unsigned long long myk;
    if (cnt <= 64) {
      unsigned long long key = ~0ull;
      if ((unsigned)lane < cnt) key = conv(cb[lane]);
#pragma unroll
      for (int k = 2; k <= 64; k <<= 1) {
#pragma unroll
        for (int j2 = k >> 1; j2 > 0; j2 >>= 1) {
          const unsigned long long o = __shfl_xor(key, j2, 64);
          const bool keepMin = (((lane & k) == 0) == ((lane & j2) == 0));
          const unsigned long long lo = o < key ? o : key;
          const unsigned long long hi = o < key ? key : o;
          key = keepMin ? lo : hi;
        }
      }
      myk = key;
    } else {
      // rare fallback: up to 256 candidates, 32 rounds of wave-argmin
      unsigned long long k0 = ~0ull, k1 = ~0ull, k2 = ~0ull, k3 = ~0ull;
      if ((unsigned)lane < cnt)         k0 = conv(cb[lane]);
      if ((unsigned)(lane + 64) < cnt)  k1 = conv(cb[lane + 64]);
      if ((unsigned)(lane + 128) < cnt) k2 = conv(cb[lane + 128]);
      if ((unsigned)(lane + 192) < cnt) k3 = conv(cb[lane + 192]);
      unsigned long long got = ~0ull;
      for (int r = 0; r < 32; ++r) {
        unsigned long long m01 = k0 < k1 ? k0 : k1;
        unsigned long long m23 = k2 < k3 ? k2 : k3;
        unsigned long long m = m01 < m23 ? m01 : m23;
#pragma unroll
        for (int s = 32; s > 0; s >>= 1) {
          const unsigned long long o = __shfl_xor(m, s, 64);
          m = o < m ? o : m;
        }
        if (lane == r) got = m;
        if (k0 == m) k0 = ~0ull;
        else if (k1 == m) k1 = ~0ull;
        else if (k2 == m) k2 = ~0ull;
        else if (k3 == m) k3 = ~0ull;
      }
      myk = got;
    }

    if (lane < KK) {
      const unsigned idx = (unsigned)(myk & 0xFFFFFFFFull);
      const float4 p = pts4[idx];
      float* __restrict__ po =
          out + ((size_t)(((size_t)b * GG + g) * KK + lane)) * 3;
      po[0] = p.x - cx; po[1] = p.y - cy; po[2] = p.z - cz;
    }
  };

  dogroup(gbase + 0, c0x, c0y, c0z, vi0);
  dogroup(gbase + 1, c1x, c1y, c1z, vi1);
  dogroup(gbase + 2, c2x, c2y, c2z, vi2);
  dogroup(gbase + 3, c3x, c3y, c3z, vi3);
}

extern "C" void kernel_launch(void* const* d_in, const int* in_sizes, int n_in,
                              void* d_out, int out_size, void* d_ws, size_t ws_size,
                              hipStream_t stream) {
  const float* xyz = (const float*)d_in[0];
  float* out = (float*)d_out;
  fps_kernel<<<dim3(BB), dim3(TFPS), 0, stream>>>(xyz, out);
  knn_kernel<<<dim3(BB * 8), dim3(512), 0, stream>>>(xyz, out);
}